// Round 2
// baseline (190.631 us; speedup 1.0000x reference)
//
#include <hip/hip_runtime.h>

typedef __attribute__((ext_vector_type(8))) short short8;
typedef __attribute__((ext_vector_type(4))) float f32x4;
typedef __attribute__((ext_vector_type(4))) unsigned int u32x4;

#define NTOK 4096
#define DIM  256
#define P_STRIDE 72        // P row stride elems (144 B); chunk kc at pos = kc ^ (2*((r>>3)&1))
#define TILE_ELEMS 32768   // ushort elems per 64KB tile image (Ks 16384 | Kt 16384)

__device__ __forceinline__ unsigned pack2bf(float a, float b) {
  unsigned ua = __builtin_bit_cast(unsigned, a) + 0x8000u;
  unsigned ub = __builtin_bit_cast(unsigned, b) + 0x8000u;
  return __builtin_amdgcn_perm(ub, ua, 0x07060302u); // low=bf16(a), high=bf16(b)
}

// ---- prologue: per-tile bf16 images (unchanged) --------------------------
// Img[b][t] = [ Ks: 64 rows x 32 chunks(16B), chunk c at (c ^ (r&7))
//             | Kt: 8 kb-blocks x 256 d x 8 tokens ]
__global__ __launch_bounds__(256, 4)
void prep_kernel(const float* __restrict__ X, unsigned short* __restrict__ Img) {
  const int b    = blockIdx.x & 3;
  const int sub  = blockIdx.x >> 2;   // 0..511
  const int t    = sub >> 3;
  const int part = sub & 7;
  const int tid  = threadIdx.x;
  const float* src = X + ((size_t)b * NTOK + t * 64) * DIM;
  unsigned short* dst = Img + ((size_t)(b * 64 + t)) * TILE_ELEMS;
  {
    int r = part * 8 + (tid >> 5);
    int c = tid & 31;
    const float* s = src + r * DIM + c * 8;
    f32x4 f0 = *(const f32x4*)s;
    f32x4 f1 = *(const f32x4*)(s + 4);
    union { unsigned u[4]; u32x4 v; } p;
    p.u[0] = pack2bf(f0[0], f0[1]);
    p.u[1] = pack2bf(f0[2], f0[3]);
    p.u[2] = pack2bf(f1[0], f1[1]);
    p.u[3] = pack2bf(f1[2], f1[3]);
    *(u32x4*)(dst + r * 256 + ((c ^ (r & 7)) << 3)) = p.v;
  }
  {
    const int d = tid;
    float f[8];
    #pragma unroll
    for (int i = 0; i < 8; ++i) f[i] = src[(part * 8 + i) * DIM + d];
    union { unsigned u[4]; u32x4 v; } p;
    p.u[0] = pack2bf(f[0], f[1]);
    p.u[1] = pack2bf(f[2], f[3]);
    p.u[2] = pack2bf(f[4], f[5]);
    p.u[3] = pack2bf(f[6], f[7]);
    *(u32x4*)(dst + 16384 + part * 2048 + d * 8) = p.v;
  }
}

// ---- flash-attention: counted-vmcnt pipeline (T3/T4), raw barriers -------
// Decomposition identical to round-1 (verified): 32-row q-tiles, 512 blocks,
// QK: wave -> (qh=wave&1 strip, role=wave>>1 key-16 group)
// PV: wave -> 32-wide d-slice, Kt from global into reg dbuf (two static sets).
// Sync: ONE raw s_barrier/iter; pre-barrier wait = vmcnt(4) lgkmcnt(0) so the
// 4 bv loads issued this iter stay in flight across the barrier; PV waits
// vmcnt(8) (drains only last iter's bv). Never vmcnt(0) in the main loop.
__global__ __launch_bounds__(512, 4)
void fa_kernel(const unsigned short* __restrict__ Img, float* __restrict__ Out) {
  __shared__ __align__(16) unsigned short ksb[2][16384];        // 64 KB (Ks dbuf)
  __shared__ __align__(16) unsigned short pb[2][32 * P_STRIDE]; //  9 KB (P dbuf)
  __shared__ __align__(16) float lbuf[32][4];                   // 0.5 KB

  const int tid  = threadIdx.x;
  const int bid  = blockIdx.x;
  const int b    = (bid & 7) >> 1;                 // XCD-pair per batch
  const int qblk = ((bid >> 3) << 1) | (bid & 1);  // 0..127 (32-row q tiles)
  const int wave = tid >> 6;
  const int lane = tid & 63;
  const int ln   = lane & 15;
  const int quad = lane >> 4;
  const int swz  = ln & 7;
  const int qh   = wave & 1;   // QK: q strip
  const int role = wave >> 1;  // QK: key-16 group

  const unsigned short* imgb  = Img + (size_t)b * 64 * TILE_ELEMS;
  const char*           imgbc = (const char*)imgb;

  // Q fragments for this wave's strip
  short8 aQ[8];
  {
    const unsigned short* qrow =
        imgb + (size_t)(qblk >> 1) * TILE_ELEMS + ((qblk & 1) * 32 + qh * 16 + ln) * 256;
    #pragma unroll
    for (int ds = 0; ds < 8; ++ds)
      aQ[ds] = *(const short8*)(qrow + (((ds * 4 + quad) ^ swz) << 3));
  }

  f32x4 o[2][2];
  #pragma unroll
  for (int s = 0; s < 2; ++s)
    #pragma unroll
    for (int dt = 0; dt < 2; ++dt) o[s][dt] = (f32x4)(0.0f);
  float lrow[4] = {0.f, 0.f, 0.f, 0.f};

  const float c2 = 0.0901684400f;  // log2(e)/sqrt(256)

  const int pwPos = ((role * 2 + (ln >> 3)) ^ ((quad >> 1) << 1)) << 3;
  const int pwCol = ln & 7;

  // Ks DMA: all 8 waves, 4 x 1KB each = 32KB
  const char* gK = imgbc + (size_t)wave * 4096 + (size_t)lane * 16;
  #pragma unroll
  for (int i = 0; i < 4; ++i)
    __builtin_amdgcn_global_load_lds(
        (const __attribute__((address_space(1))) unsigned*)(gK + i * 1024),
        (__attribute__((address_space(3))) unsigned*)(&ksb[0][wave * 2048 + i * 512]),
        16, 0, 0);

  // PV B-fragment base in Kt image: kb = ks*4+quad, d = wave*32 + dt*16 + ln
  const unsigned short* ktbase = imgb + 16384 + (size_t)quad * 2048 + (wave * 32 + ln) * 8;

  short8 bvE[2][2];  // loaded at even t
  short8 bvO[2][2];  // loaded at odd t

  // prologue barrier: Ks(0) resident (one-time full drain is fine here)
  asm volatile("s_waitcnt vmcnt(0) lgkmcnt(0)" ::: "memory");
  __builtin_amdgcn_sched_barrier(0);
  __builtin_amdgcn_s_barrier();
  __builtin_amdgcn_sched_barrier(0);

  auto iter = [&](int t, short8 (&bvLd)[2][2], short8 (&bvUs)[2][2],
                  bool doPV) __attribute__((always_inline)) {
    const int buf = t & 1;

    // 1) issue Ks(t+1) DMA (wrap at t=63 keeps wait immediates uniform)
    {
      const int tn = (t + 1) & 63;
      const char* g = gK + (size_t)tn * 65536;
      unsigned short* l = &ksb[buf ^ 1][wave * 2048];
      #pragma unroll
      for (int i = 0; i < 4; ++i)
        __builtin_amdgcn_global_load_lds(
            (const __attribute__((address_space(1))) unsigned*)(g + i * 1024),
            (__attribute__((address_space(3))) unsigned*)(l + i * 512),
            16, 0, 0);
    }
    // pin vmem issue order: DMA (4) strictly before bv (4)
    asm volatile("" ::: "memory");

    // 2) issue bv(t) = Kt(t) loads (consumed by PV at iter t+1)
    {
      const unsigned short* kt = ktbase + (size_t)t * TILE_ELEMS;
      #pragma unroll
      for (int ks = 0; ks < 2; ++ks)
        #pragma unroll
        for (int dt = 0; dt < 2; ++dt)
          bvLd[ks][dt] = *(const short8*)(kt + ks * 8192 + dt * 128);
    }

    // 3) QK(t): this wave's strip x its 16 keys
    f32x4 sf = (f32x4)(0.0f);
    {
      const unsigned short* krow = &ksb[buf][(role * 16 + ln) * 256];
      __builtin_amdgcn_s_setprio(1);
      #pragma unroll
      for (int ds = 0; ds < 8; ++ds) {
        short8 bk = *(const short8*)(krow + (((ds * 4 + quad) ^ swz) << 3));
        sf = __builtin_amdgcn_mfma_f32_16x16x32_bf16(aQ[ds], bk, sf, 0, 0, 0);
      }
      __builtin_amdgcn_s_setprio(0);
    }

    // 4) softmax numerators; packed conflict-free P store
    {
      unsigned short* pw = pb[buf];
      #pragma unroll
      for (int j = 0; j < 4; ++j) {
        float p0 = __builtin_amdgcn_exp2f(sf[j] * c2);
        lrow[j] += p0;
        unsigned q0 = __builtin_bit_cast(unsigned, p0);
        unsigned n0 = (unsigned)__builtin_amdgcn_mov_dpp((int)q0, 0xB1, 0xF, 0xF, true);
        if ((ln & 1) == 0) {
          const int r0 = qh * 16 + quad * 4 + j;
          unsigned d0 = pack2bf(__builtin_bit_cast(float, q0), __builtin_bit_cast(float, n0));
          *(unsigned*)(&pw[r0 * P_STRIDE + pwPos + pwCol]) = d0;
        }
      }
    }

    // 5) PV(t-1): needs bv(t-1) = bvUs; outstanding = [bv(t-1)4, DMA4, bv(t)4]
    if (doPV) {
      asm volatile("s_waitcnt vmcnt(8)" ::: "memory");
      __builtin_amdgcn_sched_barrier(0);
      const unsigned short* pr = pb[buf ^ 1];
      __builtin_amdgcn_s_setprio(1);
      #pragma unroll
      for (int ks = 0; ks < 2; ++ks) {
        const int pos = (ks * 4 + quad) ^ ((ln >> 3) << 1);
        short8 ap[2];
        #pragma unroll
        for (int s = 0; s < 2; ++s)
          ap[s] = *(const short8*)(&pr[(s * 16 + ln) * P_STRIDE + (pos << 3)]);
        #pragma unroll
        for (int s = 0; s < 2; ++s)
          #pragma unroll
          for (int dt = 0; dt < 2; ++dt)
            o[s][dt] = __builtin_amdgcn_mfma_f32_16x16x32_bf16(ap[s], bvUs[ks][dt], o[s][dt], 0, 0, 0);
      }
      __builtin_amdgcn_s_setprio(0);
    }

    // 6) counted pre-barrier wait: Ks(t+1) landed, bv(t) STAYS IN FLIGHT
    asm volatile("s_waitcnt vmcnt(4) lgkmcnt(0)" ::: "memory");
    __builtin_amdgcn_sched_barrier(0);
    __builtin_amdgcn_s_barrier();
    __builtin_amdgcn_sched_barrier(0);
  };

  iter(0, bvE, bvO, false);
  iter(1, bvO, bvE, true);
  #pragma unroll 1
  for (int tt = 2; tt < 64; tt += 2) {
    iter(tt, bvE, bvO, true);
    iter(tt + 1, bvO, bvE, true);
  }

  __syncthreads();  // full drain: bv(63) in regs, P(63) resident
  // final PV(63): pb[1], bvO = Kt(63)
  {
    const unsigned short* pr = pb[1];
    #pragma unroll
    for (int ks = 0; ks < 2; ++ks) {
      const int pos = (ks * 4 + quad) ^ ((ln >> 3) << 1);
      short8 ap[2];
      #pragma unroll
      for (int s = 0; s < 2; ++s)
        ap[s] = *(const short8*)(&pr[(s * 16 + ln) * P_STRIDE + (pos << 3)]);
      #pragma unroll
      for (int s = 0; s < 2; ++s)
        #pragma unroll
        for (int dt = 0; dt < 2; ++dt)
          o[s][dt] = __builtin_amdgcn_mfma_f32_16x16x32_bf16(ap[s], bvO[ks][dt], o[s][dt], 0, 0, 0);
    }
  }

  // --- merge l across the 4 roles, divide, store ---
  #pragma unroll
  for (int off = 1; off < 16; off <<= 1)
    #pragma unroll
    for (int j = 0; j < 4; ++j)
      lrow[j] += __shfl_xor(lrow[j], off, 64);
  if (ln == 0) {
    #pragma unroll
    for (int j = 0; j < 4; ++j)
      lbuf[qh * 16 + quad * 4 + j][role] = lrow[j];
  }
  __syncthreads();

  #pragma unroll
  for (int s = 0; s < 2; ++s) {
    float* outp = Out + (size_t)(b * NTOK + qblk * 32 + s * 16) * DIM + wave * 32;
    #pragma unroll
    for (int j = 0; j < 4; ++j) {
      const int row = quad * 4 + j;
      f32x4 lv = *(const f32x4*)lbuf[s * 16 + row];
      const float rl = 1.0f / (lv[0] + lv[1] + lv[2] + lv[3]);
      #pragma unroll
      for (int dt = 0; dt < 2; ++dt)
        outp[(size_t)row * DIM + dt * 16 + ln] = o[s][dt][j] * rl;
    }
  }
}

extern "C" void kernel_launch(void* const* d_in, const int* in_sizes, int n_in,
                              void* d_out, int out_size, void* d_ws, size_t ws_size,
                              hipStream_t stream) {
  const float* X = (const float*)d_in[0];       // x: fp32 [4,4096,256]
  float* Out = (float*)d_out;                   // fp32 [4,4096,256]
  unsigned short* Img = (unsigned short*)d_ws;  // 16 MB bf16 tile images
  (void)in_sizes; (void)n_in; (void)out_size; (void)ws_size;
  hipLaunchKernelGGL(prep_kernel, dim3(2048), dim3(256), 0, stream, X, Img);
  hipLaunchKernelGGL(fa_kernel, dim3(512), dim3(512), 0, stream, Img, Out);
}

// Round 3
// 172.694 us; speedup vs baseline: 1.1039x; 1.1039x over previous
//
#include <hip/hip_runtime.h>

typedef __attribute__((ext_vector_type(8))) short short8;
typedef __attribute__((ext_vector_type(4))) float f32x4;
typedef __attribute__((ext_vector_type(4))) unsigned int u32x4;

#define NTOK 4096
#define DIM  256
#define P_STRIDE 72        // P row stride elems (144 B); chunk kc at pos = kc ^ (2*((r>>3)&1))
#define TILE_ELEMS 32768   // ushort elems per 64KB tile image (Ks 16384 | Kt 16384)

__device__ __forceinline__ unsigned pack2bf(float a, float b) {
  unsigned ua = __builtin_bit_cast(unsigned, a) + 0x8000u;
  unsigned ub = __builtin_bit_cast(unsigned, b) + 0x8000u;
  return __builtin_amdgcn_perm(ub, ua, 0x07060302u); // low=bf16(a), high=bf16(b)
}

// ---- prologue v2: single X read, LDS-staged transpose --------------------
// Img[b][t] = [ Ks: 64 rows x 32 chunks(16B), chunk c at (c ^ (r&7))
//             | Kt: 8 kb-blocks x 256 d x 8 tokens ]
// Phase 1 reads 8 rows of X (f32x4, coalesced), converts ONCE via pack2bf,
// writes the Ks-swizzled image AND a linear bf16 slab in LDS.
// Phase 2 builds the transposed Kt image from LDS (banks: (d>>1)%32, 2-way = free).
// Img bits identical to the old two-pass prep (same pack2bf on same f32).
__global__ __launch_bounds__(256, 4)
void prep_kernel(const float* __restrict__ X, unsigned short* __restrict__ Img) {
  __shared__ __align__(16) unsigned short rowbf[8 * 256];  // 4 KB bf16 stage
  const int b    = blockIdx.x & 3;
  const int sub  = blockIdx.x >> 2;   // 0..511
  const int t    = sub >> 3;
  const int part = sub & 7;
  const int tid  = threadIdx.x;
  const float* src = X + ((size_t)b * NTOK + t * 64 + part * 8) * DIM;
  unsigned short* dst = Img + ((size_t)(b * 64 + t)) * TILE_ELEMS;
  {
    const int r = tid >> 5;   // row within the 8-row slab
    const int c = tid & 31;   // 16B chunk within the row
    const float* s = src + r * DIM + c * 8;
    f32x4 f0 = *(const f32x4*)s;
    f32x4 f1 = *(const f32x4*)(s + 4);
    union { unsigned u[4]; u32x4 v; } p;
    p.u[0] = pack2bf(f0[0], f0[1]);
    p.u[1] = pack2bf(f0[2], f0[3]);
    p.u[2] = pack2bf(f1[0], f1[1]);
    p.u[3] = pack2bf(f1[2], f1[3]);
    const int gr = part * 8 + r;
    *(u32x4*)(dst + gr * 256 + ((c ^ (gr & 7)) << 3)) = p.v;
    *(u32x4*)(&rowbf[r * 256 + c * 8]) = p.v;
  }
  __syncthreads();
  {
    const int d = tid;        // one column per thread
    union { unsigned short s[8]; u32x4 v; } p;
    #pragma unroll
    for (int i = 0; i < 8; ++i) p.s[i] = rowbf[i * 256 + d];
    *(u32x4*)(dst + 16384 + part * 2048 + d * 8) = p.v;
  }
}

// ---- flash-attention: uniform waves, 1 barrier/iter, P dbuf --------------
// (reverted byte-for-byte to the verified 110 µs round-0 version)
// PV: O[s][dt] += P(strips of qh) x V(d-quarter role); pos = kc ^ (2*(ln>>3))
__device__ __forceinline__ void pv_step(const unsigned short* __restrict__ pr,
                                        const unsigned short* __restrict__ kt,
                                        f32x4 (&o)[2][4],
                                        int qh, int role, int quad, int ln) {
  #pragma unroll
  for (int ks = 0; ks < 2; ++ks) {
    const int pos = (ks * 4 + quad) ^ ((ln >> 3) << 1);
    short8 ap[2], bv[4];
    #pragma unroll
    for (int s = 0; s < 2; ++s) {
      const int r = qh * 32 + s * 16 + ln;
      ap[s] = *(const short8*)(&pr[r * P_STRIDE + (pos << 3)]);
    }
    const unsigned short* kb = kt + (ks * 4 + quad) * 2048 + (role * 64 + ln) * 8;
    #pragma unroll
    for (int dt = 0; dt < 4; ++dt) bv[dt] = *(const short8*)(kb + dt * 128);
    #pragma unroll
    for (int s = 0; s < 2; ++s)
      #pragma unroll
      for (int dt = 0; dt < 4; ++dt)
        o[s][dt] = __builtin_amdgcn_mfma_f32_16x16x32_bf16(ap[s], bv[dt], o[s][dt], 0, 0, 0);
  }
}

__global__ __launch_bounds__(512, 1)
void fa_kernel(const unsigned short* __restrict__ Img, float* __restrict__ Out) {
  __shared__ __align__(16) unsigned short ksb[2][16384];        // 64 KB
  __shared__ __align__(16) unsigned short ktb[2][16384];        // 64 KB
  __shared__ __align__(16) unsigned short pb[2][64 * P_STRIDE]; // 18 KB
  __shared__ float lbuf[64][4];                                 // 1 KB

  const int tid  = threadIdx.x;
  const int b    = blockIdx.x & 3;
  const int qblk = blockIdx.x >> 2;
  const int wave = tid >> 6;
  const int lane = tid & 63;
  const int ln   = lane & 15;
  const int quad = lane >> 4;
  const int swz  = ln & 7;
  const int qh   = wave & 1;
  const int role = wave >> 1;

  const unsigned short* imgb  = Img + (size_t)b * 64 * TILE_ELEMS;
  const char*           imgbc = (const char*)imgb;

  short8 aQ[2][8];
  #pragma unroll
  for (int s = 0; s < 2; ++s) {
    const unsigned short* qrow =
        imgb + (size_t)qblk * TILE_ELEMS + (qh * 32 + s * 16 + ln) * 256;
    #pragma unroll
    for (int ds = 0; ds < 8; ++ds)
      aQ[s][ds] = *(const short8*)(qrow + (((ds * 4 + quad) ^ swz) << 3));
  }

  f32x4 o[2][4];
  #pragma unroll
  for (int s = 0; s < 2; ++s)
    #pragma unroll
    for (int dt = 0; dt < 4; ++dt) o[s][dt] = (f32x4)(0.0f);
  float lrow[2][4] = {{0.f,0.f,0.f,0.f},{0.f,0.f,0.f,0.f}};

  const float c2 = 0.0901684400f;  // log2(e)/sqrt(256)

  // P write constants: kc = role*2 + (ln>>3); pos = kc ^ (2*(quad>>1))
  const int pwPos = ((role * 2 + (ln >> 3)) ^ ((quad >> 1) << 1)) << 3;
  const int pwCol = ln & 7;  // even lanes write dword covering cols (pwCol, pwCol+1)

  const bool dmaKs = wave < 4;
  const int  dmaQ  = wave & 3;
  const char* gK = imgbc + (size_t)dmaQ * 8192 + (size_t)lane * 16;

  if (dmaKs) {
    #pragma unroll
    for (int i = 0; i < 8; ++i)
      __builtin_amdgcn_global_load_lds(
          (const __attribute__((address_space(1))) unsigned*)(gK + i * 1024),
          (__attribute__((address_space(3))) unsigned*)(&ksb[0][dmaQ * 4096 + i * 512]),
          16, 0, 0);
  }

  for (int t = 0; t < 64; ++t) {
    __syncthreads();  // drains last iter's DMA; P(t-1)/Ks(t)/Kt(t-1) ready
    const int buf = t & 1;

    if (dmaKs) {
      if (t < 63) {
        const char* g = gK + (size_t)(t + 1) * 65536;
        unsigned short* l = &ksb[buf ^ 1][dmaQ * 4096];
        #pragma unroll
        for (int i = 0; i < 8; ++i)
          __builtin_amdgcn_global_load_lds(
              (const __attribute__((address_space(1))) unsigned*)(g + i * 1024),
              (__attribute__((address_space(3))) unsigned*)(l + i * 512),
              16, 0, 0);
      }
    } else {
      const char* g = gK + (size_t)t * 65536 + 32768;
      unsigned short* l = &ktb[buf][dmaQ * 4096];
      #pragma unroll
      for (int i = 0; i < 8; ++i)
        __builtin_amdgcn_global_load_lds(
            (const __attribute__((address_space(1))) unsigned*)(g + i * 1024),
            (__attribute__((address_space(3))) unsigned*)(l + i * 512),
            16, 0, 0);
    }

    // --- QK(t): keys role*16..+15, both strips ---
    f32x4 sf0 = (f32x4)(0.0f), sf1 = (f32x4)(0.0f);
    {
      const unsigned short* krow = &ksb[buf][(role * 16 + ln) * 256];
      #pragma unroll
      for (int ds = 0; ds < 8; ++ds) {
        short8 bk = *(const short8*)(krow + (((ds * 4 + quad) ^ swz) << 3));
        sf0 = __builtin_amdgcn_mfma_f32_16x16x32_bf16(aQ[0][ds], bk, sf0, 0, 0, 0);
        sf1 = __builtin_amdgcn_mfma_f32_16x16x32_bf16(aQ[1][ds], bk, sf1, 0, 0, 0);
      }
    }
    // --- softmax numerators; packed conflict-free P store ---
    {
      unsigned short* pw = pb[buf];
      #pragma unroll
      for (int j = 0; j < 4; ++j) {
        float p0 = __builtin_amdgcn_exp2f(sf0[j] * c2);
        float p1 = __builtin_amdgcn_exp2f(sf1[j] * c2);
        lrow[0][j] += p0;
        lrow[1][j] += p1;
        unsigned q0 = __builtin_bit_cast(unsigned, p0);
        unsigned q1 = __builtin_bit_cast(unsigned, p1);
        // partner (lane^1) via DPP quad_perm [1,0,3,2] = 0xB1 (pure VALU)
        unsigned n0 = (unsigned)__builtin_amdgcn_mov_dpp((int)q0, 0xB1, 0xF, 0xF, true);
        unsigned n1 = (unsigned)__builtin_amdgcn_mov_dpp((int)q1, 0xB1, 0xF, 0xF, true);
        if ((ln & 1) == 0) {
          const int r0 = qh * 32 + quad * 4 + j;
          unsigned d0 = pack2bf(__builtin_bit_cast(float, q0), __builtin_bit_cast(float, n0));
          unsigned d1 = pack2bf(__builtin_bit_cast(float, q1), __builtin_bit_cast(float, n1));
          *(unsigned*)(&pw[r0 * P_STRIDE + pwPos + pwCol]) = d0;
          *(unsigned*)(&pw[(r0 + 16) * P_STRIDE + pwPos + pwCol]) = d1;
        }
      }
    }

    // --- PV(t-1): d-quarter role*64..+63, both strips, all 64 keys ---
    if (t > 0)
      pv_step(pb[buf ^ 1], ktb[buf ^ 1], o, qh, role, quad, ln);
  }

  __syncthreads();  // P(63), Kt(63) resident
  pv_step(pb[1], ktb[1], o, qh, role, quad, ln);  // final tile

  // --- merge l across the 4 roles, divide, store ---
  #pragma unroll
  for (int off = 1; off < 16; off <<= 1)
    #pragma unroll
    for (int s = 0; s < 2; ++s)
      #pragma unroll
      for (int j = 0; j < 4; ++j)
        lrow[s][j] += __shfl_xor(lrow[s][j], off, 64);
  if (ln == 0) {
    #pragma unroll
    for (int s = 0; s < 2; ++s)
      #pragma unroll
      for (int j = 0; j < 4; ++j)
        lbuf[qh * 32 + s * 16 + quad * 4 + j][role] = lrow[s][j];
  }
  __syncthreads();

  #pragma unroll
  for (int s = 0; s < 2; ++s) {
    float* outp = Out + (size_t)(b * NTOK + qblk * 64 + qh * 32 + s * 16) * DIM + role * 64;
    #pragma unroll
    for (int j = 0; j < 4; ++j) {
      const int row = s * 16 + quad * 4 + j;
      f32x4 lv = *(const f32x4*)lbuf[qh * 32 + row];
      const float rl = 1.0f / (lv[0] + lv[1] + lv[2] + lv[3]);
      #pragma unroll
      for (int dt = 0; dt < 4; ++dt)
        outp[(size_t)(quad * 4 + j) * DIM + dt * 16 + ln] = o[s][dt][j] * rl;
    }
  }
}

extern "C" void kernel_launch(void* const* d_in, const int* in_sizes, int n_in,
                              void* d_out, int out_size, void* d_ws, size_t ws_size,
                              hipStream_t stream) {
  const float* X = (const float*)d_in[0];       // x: fp32 [4,4096,256]
  float* Out = (float*)d_out;                   // fp32 [4,4096,256]
  unsigned short* Img = (unsigned short*)d_ws;  // 16 MB bf16 tile images
  (void)in_sizes; (void)n_in; (void)out_size; (void)ws_size;
  hipLaunchKernelGGL(prep_kernel, dim3(2048), dim3(256), 0, stream, X, Img);
  hipLaunchKernelGGL(fa_kernel, dim3(256), dim3(512), 0, stream, Img, Out);
}

// Round 4
// 165.736 us; speedup vs baseline: 1.1502x; 1.0420x over previous
//
#include <hip/hip_runtime.h>

typedef __attribute__((ext_vector_type(8))) short short8;
typedef __attribute__((ext_vector_type(4))) float f32x4;
typedef __attribute__((ext_vector_type(4))) unsigned int u32x4;

#define NTOK 4096
#define DIM  256
#define P_STRIDE 72        // P row stride elems (144 B); chunk kc at pos = kc ^ (2*((r>>3)&1))
#define TILE_ELEMS 32768   // ushort elems per 64KB tile image (Ks 16384 | Kt 16384)

__device__ __forceinline__ unsigned pack2bf(float a, float b) {
  unsigned ua = __builtin_bit_cast(unsigned, a) + 0x8000u;
  unsigned ub = __builtin_bit_cast(unsigned, b) + 0x8000u;
  return __builtin_amdgcn_perm(ub, ua, 0x07060302u); // low=bf16(a), high=bf16(b)
}

// ---- prologue v2: single X read, LDS-staged transpose (verified R3) ------
__global__ __launch_bounds__(256, 4)
void prep_kernel(const float* __restrict__ X, unsigned short* __restrict__ Img) {
  __shared__ __align__(16) unsigned short rowbf[8 * 256];  // 4 KB bf16 stage
  const int b    = blockIdx.x & 3;
  const int sub  = blockIdx.x >> 2;   // 0..511
  const int t    = sub >> 3;
  const int part = sub & 7;
  const int tid  = threadIdx.x;
  const float* src = X + ((size_t)b * NTOK + t * 64 + part * 8) * DIM;
  unsigned short* dst = Img + ((size_t)(b * 64 + t)) * TILE_ELEMS;
  {
    const int r = tid >> 5;   // row within the 8-row slab
    const int c = tid & 31;   // 16B chunk within the row
    const float* s = src + r * DIM + c * 8;
    f32x4 f0 = *(const f32x4*)s;
    f32x4 f1 = *(const f32x4*)(s + 4);
    union { unsigned u[4]; u32x4 v; } p;
    p.u[0] = pack2bf(f0[0], f0[1]);
    p.u[1] = pack2bf(f0[2], f0[3]);
    p.u[2] = pack2bf(f1[0], f1[1]);
    p.u[3] = pack2bf(f1[2], f1[3]);
    const int gr = part * 8 + r;
    *(u32x4*)(dst + gr * 256 + ((c ^ (gr & 7)) << 3)) = p.v;
    *(u32x4*)(&rowbf[r * 256 + c * 8]) = p.v;
  }
  __syncthreads();
  {
    const int d = tid;        // one column per thread
    union { unsigned short s[8]; u32x4 v; } p;
    #pragma unroll
    for (int i = 0; i < 8; ++i) p.s[i] = rowbf[i * 256 + d];
    *(u32x4*)(dst + 16384 + part * 2048 + d * 8) = p.v;
  }
}

// ---- flash-attention: R0 structure, P-store sunk below PV ----------------
// Per iter: QK(t) -> softmax-COMPUTE(t) (regs only) -> PV(t-1) -> P-STORE(t).
// Moving the ds_writes after pv_step removes the pb[buf]/pb[buf^1] aliasing
// pin, letting the scheduler interleave the exp-chain VALU with PV's
// ds_read/MFMA (previously fully serialized: 30% MFMA + 29% VALU + 46% LDS
// summed to the wall).
__device__ __forceinline__ void pv_step(const unsigned short* __restrict__ pr,
                                        const unsigned short* __restrict__ kt,
                                        f32x4 (&o)[2][4],
                                        int qh, int role, int quad, int ln) {
  #pragma unroll
  for (int ks = 0; ks < 2; ++ks) {
    const int pos = (ks * 4 + quad) ^ ((ln >> 3) << 1);
    short8 ap[2], bv[4];
    #pragma unroll
    for (int s = 0; s < 2; ++s) {
      const int r = qh * 32 + s * 16 + ln;
      ap[s] = *(const short8*)(&pr[r * P_STRIDE + (pos << 3)]);
    }
    const unsigned short* kb = kt + (ks * 4 + quad) * 2048 + (role * 64 + ln) * 8;
    #pragma unroll
    for (int dt = 0; dt < 4; ++dt) bv[dt] = *(const short8*)(kb + dt * 128);
    #pragma unroll
    for (int s = 0; s < 2; ++s)
      #pragma unroll
      for (int dt = 0; dt < 4; ++dt)
        o[s][dt] = __builtin_amdgcn_mfma_f32_16x16x32_bf16(ap[s], bv[dt], o[s][dt], 0, 0, 0);
  }
}

__global__ __launch_bounds__(512, 1)
void fa_kernel(const unsigned short* __restrict__ Img, float* __restrict__ Out) {
  __shared__ __align__(16) unsigned short ksb[2][16384];        // 64 KB
  __shared__ __align__(16) unsigned short ktb[2][16384];        // 64 KB
  __shared__ __align__(16) unsigned short pb[2][64 * P_STRIDE]; // 18 KB
  __shared__ float lbuf[64][4];                                 // 1 KB

  const int tid  = threadIdx.x;
  const int b    = blockIdx.x & 3;
  const int qblk = blockIdx.x >> 2;
  const int wave = tid >> 6;
  const int lane = tid & 63;
  const int ln   = lane & 15;
  const int quad = lane >> 4;
  const int swz  = ln & 7;
  const int qh   = wave & 1;
  const int role = wave >> 1;

  const unsigned short* imgb  = Img + (size_t)b * 64 * TILE_ELEMS;
  const char*           imgbc = (const char*)imgb;

  short8 aQ[2][8];
  #pragma unroll
  for (int s = 0; s < 2; ++s) {
    const unsigned short* qrow =
        imgb + (size_t)qblk * TILE_ELEMS + (qh * 32 + s * 16 + ln) * 256;
    #pragma unroll
    for (int ds = 0; ds < 8; ++ds)
      aQ[s][ds] = *(const short8*)(qrow + (((ds * 4 + quad) ^ swz) << 3));
  }

  f32x4 o[2][4];
  #pragma unroll
  for (int s = 0; s < 2; ++s)
    #pragma unroll
    for (int dt = 0; dt < 4; ++dt) o[s][dt] = (f32x4)(0.0f);
  float lrow[2][4] = {{0.f,0.f,0.f,0.f},{0.f,0.f,0.f,0.f}};

  const float c2 = 0.0901684400f;  // log2(e)/sqrt(256)

  // P write constants: kc = role*2 + (ln>>3); pos = kc ^ (2*(quad>>1))
  const int pwPos = ((role * 2 + (ln >> 3)) ^ ((quad >> 1) << 1)) << 3;
  const int pwCol = ln & 7;  // even lanes write dword covering cols (pwCol, pwCol+1)

  const bool dmaKs = wave < 4;
  const int  dmaQ  = wave & 3;
  const char* gK = imgbc + (size_t)dmaQ * 8192 + (size_t)lane * 16;

  if (dmaKs) {
    #pragma unroll
    for (int i = 0; i < 8; ++i)
      __builtin_amdgcn_global_load_lds(
          (const __attribute__((address_space(1))) unsigned*)(gK + i * 1024),
          (__attribute__((address_space(3))) unsigned*)(&ksb[0][dmaQ * 4096 + i * 512]),
          16, 0, 0);
  }

  for (int t = 0; t < 64; ++t) {
    __syncthreads();  // drains last iter's DMA; P(t-1)/Ks(t)/Kt(t-1) ready
    const int buf = t & 1;

    if (dmaKs) {
      if (t < 63) {
        const char* g = gK + (size_t)(t + 1) * 65536;
        unsigned short* l = &ksb[buf ^ 1][dmaQ * 4096];
        #pragma unroll
        for (int i = 0; i < 8; ++i)
          __builtin_amdgcn_global_load_lds(
              (const __attribute__((address_space(1))) unsigned*)(g + i * 1024),
              (__attribute__((address_space(3))) unsigned*)(l + i * 512),
              16, 0, 0);
      }
    } else {
      const char* g = gK + (size_t)t * 65536 + 32768;
      unsigned short* l = &ktb[buf][dmaQ * 4096];
      #pragma unroll
      for (int i = 0; i < 8; ++i)
        __builtin_amdgcn_global_load_lds(
            (const __attribute__((address_space(1))) unsigned*)(g + i * 1024),
            (__attribute__((address_space(3))) unsigned*)(l + i * 512),
            16, 0, 0);
    }

    // --- QK(t): keys role*16..+15, both strips ---
    f32x4 sf0 = (f32x4)(0.0f), sf1 = (f32x4)(0.0f);
    {
      const unsigned short* krow = &ksb[buf][(role * 16 + ln) * 256];
      #pragma unroll
      for (int ds = 0; ds < 8; ++ds) {
        short8 bk = *(const short8*)(krow + (((ds * 4 + quad) ^ swz) << 3));
        sf0 = __builtin_amdgcn_mfma_f32_16x16x32_bf16(aQ[0][ds], bk, sf0, 0, 0, 0);
        sf1 = __builtin_amdgcn_mfma_f32_16x16x32_bf16(aQ[1][ds], bk, sf1, 0, 0, 0);
      }
    }

    // --- softmax numerators: COMPUTE ONLY (held in regs; stored after PV) ---
    unsigned pd0[4], pd1[4];
    #pragma unroll
    for (int j = 0; j < 4; ++j) {
      float p0 = __builtin_amdgcn_exp2f(sf0[j] * c2);
      float p1 = __builtin_amdgcn_exp2f(sf1[j] * c2);
      lrow[0][j] += p0;
      lrow[1][j] += p1;
      unsigned q0 = __builtin_bit_cast(unsigned, p0);
      unsigned q1 = __builtin_bit_cast(unsigned, p1);
      // partner (lane^1) via DPP quad_perm [1,0,3,2] = 0xB1 (pure VALU)
      unsigned n0 = (unsigned)__builtin_amdgcn_mov_dpp((int)q0, 0xB1, 0xF, 0xF, true);
      unsigned n1 = (unsigned)__builtin_amdgcn_mov_dpp((int)q1, 0xB1, 0xF, 0xF, true);
      pd0[j] = pack2bf(__builtin_bit_cast(float, q0), __builtin_bit_cast(float, n0));
      pd1[j] = pack2bf(__builtin_bit_cast(float, q1), __builtin_bit_cast(float, n1));
    }

    // --- PV(t-1): d-quarter role*64..+63, both strips, all 64 keys ---
    if (t > 0)
      pv_step(pb[buf ^ 1], ktb[buf ^ 1], o, qh, role, quad, ln);

    // --- P-STORE(t): after PV's reads -> no alias pin, scheduler is free ---
    if ((ln & 1) == 0) {
      unsigned short* pw = pb[buf];
      #pragma unroll
      for (int j = 0; j < 4; ++j) {
        const int r0 = qh * 32 + quad * 4 + j;
        *(unsigned*)(&pw[r0 * P_STRIDE + pwPos + pwCol]) = pd0[j];
        *(unsigned*)(&pw[(r0 + 16) * P_STRIDE + pwPos + pwCol]) = pd1[j];
      }
    }
  }

  __syncthreads();  // P(63), Kt(63) resident
  pv_step(pb[1], ktb[1], o, qh, role, quad, ln);  // final tile

  // --- merge l across the 4 roles, divide, store ---
  #pragma unroll
  for (int off = 1; off < 16; off <<= 1)
    #pragma unroll
    for (int s = 0; s < 2; ++s)
      #pragma unroll
      for (int j = 0; j < 4; ++j)
        lrow[s][j] += __shfl_xor(lrow[s][j], off, 64);
  if (ln == 0) {
    #pragma unroll
    for (int s = 0; s < 2; ++s)
      #pragma unroll
      for (int j = 0; j < 4; ++j)
        lbuf[qh * 32 + s * 16 + quad * 4 + j][role] = lrow[s][j];
  }
  __syncthreads();

  #pragma unroll
  for (int s = 0; s < 2; ++s) {
    float* outp = Out + (size_t)(b * NTOK + qblk * 64 + qh * 32 + s * 16) * DIM + role * 64;
    #pragma unroll
    for (int j = 0; j < 4; ++j) {
      const int row = s * 16 + quad * 4 + j;
      f32x4 lv = *(const f32x4*)lbuf[qh * 32 + row];
      const float rl = 1.0f / (lv[0] + lv[1] + lv[2] + lv[3]);
      #pragma unroll
      for (int dt = 0; dt < 4; ++dt)
        outp[(size_t)(quad * 4 + j) * DIM + dt * 16 + ln] = o[s][dt][j] * rl;
    }
  }
}

extern "C" void kernel_launch(void* const* d_in, const int* in_sizes, int n_in,
                              void* d_out, int out_size, void* d_ws, size_t ws_size,
                              hipStream_t stream) {
  const float* X = (const float*)d_in[0];       // x: fp32 [4,4096,256]
  float* Out = (float*)d_out;                   // fp32 [4,4096,256]
  unsigned short* Img = (unsigned short*)d_ws;  // 16 MB bf16 tile images
  (void)in_sizes; (void)n_in; (void)out_size; (void)ws_size;
  hipLaunchKernelGGL(prep_kernel, dim3(2048), dim3(256), 0, stream, X, Img);
  hipLaunchKernelGGL(fa_kernel, dim3(256), dim3(512), 0, stream, Img, Out);
}